// Round 10
// baseline (837.545 us; speedup 1.0000x reference)
//
#include <hip/hip_runtime.h>

// Grouped GEMM (ragged rows over 8 experts) + dequant epilogue.
// R10: faithful 8-phase 256x256 schedule with race-safe stage stagger.
// Phases per K-tile (BK=64): p1 (af03xbf01, 12 reads), p2 (af03xbf23, 4),
// p3 (af47xbf23, 8; stage B(t+2)), p4 (af47xbf01, 0; stage A(t+2), vmcnt(8)).
// Each staged half writes LDS only after its previous tenant's last ds_read
// has been barrier-confirmed. 2 barriers/phase, setprio, T1+T2 swizzles.

#define KDIM 2048
#define NT 32   // K tiles of 64

typedef __attribute__((ext_vector_type(4))) float f32x4;
typedef __attribute__((ext_vector_type(4))) unsigned int u32x4;
using frag_ab = __attribute__((ext_vector_type(8))) short;
using frag_cd = __attribute__((ext_vector_type(4))) float;

__device__ __forceinline__ unsigned int pack_bf2(float x, float y) {
  unsigned int ux = __float_as_uint(x);
  unsigned int uy = __float_as_uint(y);
  ux += 0x7fffu + ((ux >> 16) & 1u);
  uy += 0x7fffu + ((uy >> 16) & 1u);
  return (ux >> 16) | (uy & 0xffff0000u);
}

__device__ __forceinline__ void gload_lds16(const void* g, void* lds) {
  __builtin_amdgcn_global_load_lds(
      (const __attribute__((address_space(1))) unsigned int*)g,
      (__attribute__((address_space(3))) unsigned int*)lds, 16, 0, 0);
}

#define BARRIER() asm volatile("s_barrier" ::: "memory")

// ---------------- convert pass: f32 -> bf16 into ws ----------------
__global__ __launch_bounds__(256)
void convert_kernel(const float* __restrict__ A, const float* __restrict__ B,
                    unsigned short* __restrict__ wa, unsigned short* __restrict__ wb) {
  constexpr long long NA = 16384LL * 2048;
  constexpr long long NB = 8LL * 5632 * 2048;
  constexpr long long NA8 = NA / 8;
  constexpr long long NTOT = (NA + NB) / 8;
  for (long long c = (long long)blockIdx.x * 256 + threadIdx.x; c < NTOT;
       c += (long long)gridDim.x * 256) {
    const float* src;
    unsigned short* dst;
    long long off;
    if (c < NA8) { src = A; dst = wa; off = c * 8; }
    else         { src = B; dst = wb; off = (c - NA8) * 8; }
    f32x4 v0 = *(const f32x4*)(src + off);
    f32x4 v1 = *(const f32x4*)(src + off + 4);
    u32x4 o;
    o[0] = pack_bf2(v0[0], v0[1]);
    o[1] = pack_bf2(v0[2], v0[3]);
    o[2] = pack_bf2(v1[0], v1[1]);
    o[3] = pack_bf2(v1[2], v1[3]);
    *(u32x4*)(dst + off) = o;
  }
}

// ---------------- 8-phase bf16 grouped GEMM ----------------
// LDS: A[2][256*64], B[2][256*64] bf16 = 128 KiB. Swizzle: phys 16B-chunk
// p of row r holds logical chunk p ^ (r&7); linear gload dest + pre-permuted
// global source + XOR'd ds_read (rule 21, verified R5/R9: 0 conflicts).
__global__ __launch_bounds__(512, 1)
void ggemm_p8(const unsigned short* __restrict__ A,
              const unsigned short* __restrict__ B,
              const float* __restrict__ sa,
              const float* __restrict__ sb,
              const int* __restrict__ seg,
              float* __restrict__ C) {
  constexpr int M = 16384, N = 5632, E = 8;
  constexpr int NTC = N / 256;          // 22
  const int nwg = (M / 256) * NTC;      // 1408, % 8 == 0

  int bid = blockIdx.x;
  int sid = (bid & 7) * (nwg >> 3) + (bid >> 3);  // T1
  int mt = sid / NTC, nt = sid % NTC;
  int m0 = mt * 256, n0 = nt * 256;

  int tid = threadIdx.x, lane = tid & 63, w = tid >> 6;
  int l16 = lane & 15, lhi = lane >> 4;
  int wrow = (w >> 2) * 128;   // 2 wave-rows
  int wcol = (w & 3) * 64;     // 4 wave-cols

  __shared__ unsigned short Asm[2][256 * 64];
  __shared__ unsigned short Bsm[2][256 * 64];

  // stage source coords (pre-permuted)
  int srow = lane >> 3;
  int scol = ((lane & 7) ^ srow) * 8;
  const unsigned short* gA = A + (size_t)(m0 + w * 16 + srow) * KDIM + scol;

  // swizzled ds_read chunk offsets
  int c7 = l16 & 7;
  int x0 = (lhi ^ c7) * 8;
  int x1 = ((4 | lhi) ^ c7) * 8;
  int offA[8], offB[4];
#pragma unroll
  for (int f = 0; f < 8; ++f) offA[f] = (wrow + f * 16 + l16) * 64;
#pragma unroll
  for (int g = 0; g < 4; ++g) offB[g] = (wcol + g * 16 + l16) * 64;

  for (int e = 0; e < E; ++e) {
    int rlo = max(m0, seg[e]);
    int rhi = min(m0 + 256, seg[e + 1]);
    if (rlo >= rhi) continue;  // block-uniform
    const unsigned short* gB =
        B + (size_t)e * N * KDIM + (size_t)(n0 + w * 16 + srow) * KDIM + scol;

    frag_cd acc[8][4];
#pragma unroll
    for (int f = 0; f < 8; ++f)
#pragma unroll
      for (int g = 0; g < 4; ++g) acc[f][g] = (frag_cd){0.f, 0.f, 0.f, 0.f};

    auto stA = [&](int b, int h, int t) {
#pragma unroll
      for (int i = 0; i < 2; ++i)
        gload_lds16(gA + (size_t)(h * 128 + i * 8) * KDIM + t * 64,
                    &Asm[b][(h * 128 + w * 16 + i * 8) * 64]);
    };
    auto stB = [&](int b, int h, int t) {
#pragma unroll
      for (int i = 0; i < 2; ++i)
        gload_lds16(gB + (size_t)(h * 128 + i * 8) * KDIM + t * 64,
                    &Bsm[b][(h * 128 + w * 16 + i * 8) * 64]);
    };

    // ---- prologue: tiles 0 and 1 fully staged ----
    stA(0, 0, 0); stA(0, 1, 0); stB(0, 0, 0); stB(0, 1, 0);
    stA(1, 0, 1); stA(1, 1, 1); stB(1, 0, 1); stB(1, 1, 1);
    asm volatile("s_waitcnt vmcnt(8)" ::: "memory");
    BARRIER();

    for (int t = 0; t < NT; ++t) {
      const int b = t & 1;
      const unsigned short* pa = &Asm[b][0];
      const unsigned short* pb = &Bsm[b][0];
      frag_ab af[2][4], bf01[2][2], bf23[2][2];

      // ===== p1: read af03 (8) + bf01 (4); MFMA f0-3 x g0-1 =====
#pragma unroll
      for (int f = 0; f < 4; ++f) {
        af[0][f] = *(const frag_ab*)(pa + offA[f] + x0);
        af[1][f] = *(const frag_ab*)(pa + offA[f] + x1);
      }
#pragma unroll
      for (int g = 0; g < 2; ++g) {
        bf01[0][g] = *(const frag_ab*)(pb + offB[g] + x0);
        bf01[1][g] = *(const frag_ab*)(pb + offB[g] + x1);
      }
      asm volatile("s_waitcnt lgkmcnt(8)" ::: "memory");
      BARRIER();
      __builtin_amdgcn_s_setprio(1);
#pragma unroll
      for (int f = 0; f < 4; ++f)
#pragma unroll
        for (int g = 0; g < 2; ++g)
#pragma unroll
          for (int ks = 0; ks < 2; ++ks)
            acc[f][g] = __builtin_amdgcn_mfma_f32_16x16x32_bf16(
                af[ks][f], bf01[ks][g], acc[f][g], 0, 0, 0);
      __builtin_amdgcn_s_setprio(0);
      BARRIER();

      // ===== p2: read bf23 (4); MFMA f0-3 x g2-3 =====
#pragma unroll
      for (int g = 0; g < 2; ++g) {
        bf23[0][g] = *(const frag_ab*)(pb + offB[2 + g] + x0);
        bf23[1][g] = *(const frag_ab*)(pb + offB[2 + g] + x1);
      }
      BARRIER();
      __builtin_amdgcn_s_setprio(1);
#pragma unroll
      for (int f = 0; f < 4; ++f)
#pragma unroll
        for (int g = 0; g < 2; ++g)
#pragma unroll
          for (int ks = 0; ks < 2; ++ks)
            acc[f][2 + g] = __builtin_amdgcn_mfma_f32_16x16x32_bf16(
                af[ks][f], bf23[ks][g], acc[f][2 + g], 0, 0, 0);
      __builtin_amdgcn_s_setprio(0);
      BARRIER();

      // ===== p3: read af47 (8); stage B(t+2); MFMA f4-7 x g2-3 =====
#pragma unroll
      for (int f = 0; f < 4; ++f) {
        af[0][f] = *(const frag_ab*)(pa + offA[4 + f] + x0);
        af[1][f] = *(const frag_ab*)(pa + offA[4 + f] + x1);
      }
      if (t + 2 < NT) { stB(b, 0, t + 2); stB(b, 1, t + 2); }
      BARRIER();
      __builtin_amdgcn_s_setprio(1);
#pragma unroll
      for (int f = 0; f < 4; ++f)
#pragma unroll
        for (int g = 0; g < 2; ++g)
#pragma unroll
          for (int ks = 0; ks < 2; ++ks)
            acc[4 + f][2 + g] = __builtin_amdgcn_mfma_f32_16x16x32_bf16(
                af[ks][f], bf23[ks][g], acc[4 + f][2 + g], 0, 0, 0);
      __builtin_amdgcn_s_setprio(0);
      BARRIER();

      // ===== p4: stage A(t+2); vmcnt; MFMA f4-7 x g0-1 =====
      if (t + 2 < NT) {
        stA(b, 0, t + 2); stA(b, 1, t + 2);
        asm volatile("s_waitcnt vmcnt(8)" ::: "memory");
      } else {
        asm volatile("s_waitcnt vmcnt(0)" ::: "memory");
      }
      BARRIER();
      __builtin_amdgcn_s_setprio(1);
#pragma unroll
      for (int f = 0; f < 4; ++f)
#pragma unroll
        for (int g = 0; g < 2; ++g)
#pragma unroll
          for (int ks = 0; ks < 2; ++ks)
            acc[4 + f][g] = __builtin_amdgcn_mfma_f32_16x16x32_bf16(
                af[ks][f], bf01[ks][g], acc[4 + f][g], 0, 0, 0);
      __builtin_amdgcn_s_setprio(0);
      BARRIER();
    }

    // ---- epilogue: dequant + masked store ----
    float sbe = sb[e];
#pragma unroll
    for (int f = 0; f < 8; ++f) {
#pragma unroll
      for (int r = 0; r < 4; ++r) {
        int grow = m0 + wrow + f * 16 + lhi * 4 + r;
        if (grow >= rlo && grow < rhi) {
          float s = sa[grow] * sbe;
          float* Crow = C + (size_t)grow * N + n0 + wcol;
#pragma unroll
          for (int g = 0; g < 4; ++g)
            Crow[g * 16 + l16] = acc[f][g][r] * s;
        }
      }
    }
  }
}

extern "C" void kernel_launch(void* const* d_in, const int* in_sizes, int n_in,
                              void* d_out, int out_size, void* d_ws, size_t ws_size,
                              hipStream_t stream) {
  const float* a = (const float*)d_in[0];
  const float* b = (const float*)d_in[1];
  const float* sa = (const float*)d_in[2];
  const float* sb = (const float*)d_in[3];
  const int* seg = (const int*)d_in[4];
  float* out = (float*)d_out;

  constexpr size_t NA = 16384ULL * 2048;
  unsigned short* wa = (unsigned short*)d_ws;
  unsigned short* wb = wa + NA;

  hipLaunchKernelGGL(convert_kernel, dim3(2048), dim3(256), 0, stream, a, b, wa, wb);
  hipLaunchKernelGGL(ggemm_p8, dim3((16384 / 256) * (5632 / 256)), dim3(512), 0,
                     stream, wa, wb, sa, sb, seg, out);
}

// Round 11
// 822.811 us; speedup vs baseline: 1.0179x; 1.0179x over previous
//
#include <hip/hip_runtime.h>

// Grouped GEMM (ragged rows over 8 experts) + dequant epilogue.
// R11 = R9 skeleton (BK=64, 128x128, 2-phase, gload_lds16 issue-early, T1,
// verified XOR swizzle) with 32x32x16 MFMA: half the MFMA instruction count,
// +15% matrix rate (2382 vs 2075 TF), same LDS traffic.

#define BK 64
#define NKSTEP 32   // 2048/64
#define KDIM 2048

typedef __attribute__((ext_vector_type(4))) float f32x4;
typedef __attribute__((ext_vector_type(4))) unsigned int u32x4;
using frag_ab = __attribute__((ext_vector_type(8))) short;   // 8 bf16
using frag_cd16 = __attribute__((ext_vector_type(16))) float; // 32x32 acc

__device__ __forceinline__ unsigned int pack_bf2(float x, float y) {
  unsigned int ux = __float_as_uint(x);
  unsigned int uy = __float_as_uint(y);
  ux += 0x7fffu + ((ux >> 16) & 1u);
  uy += 0x7fffu + ((uy >> 16) & 1u);
  return (ux >> 16) | (uy & 0xffff0000u);
}

__device__ __forceinline__ void gload_lds16(const void* g, void* lds) {
  __builtin_amdgcn_global_load_lds(
      (const __attribute__((address_space(1))) unsigned int*)g,
      (__attribute__((address_space(3))) unsigned int*)lds, 16, 0, 0);
}

// ---------------- convert pass: f32 -> bf16 into ws ----------------
__global__ __launch_bounds__(256)
void convert_kernel(const float* __restrict__ A, const float* __restrict__ B,
                    unsigned short* __restrict__ wa, unsigned short* __restrict__ wb) {
  constexpr long long NA = 16384LL * 2048;
  constexpr long long NB = 8LL * 5632 * 2048;
  constexpr long long NA8 = NA / 8;
  constexpr long long NTOT = (NA + NB) / 8;
  for (long long c = (long long)blockIdx.x * 256 + threadIdx.x; c < NTOT;
       c += (long long)gridDim.x * 256) {
    const float* src;
    unsigned short* dst;
    long long off;
    if (c < NA8) { src = A; dst = wa; off = c * 8; }
    else         { src = B; dst = wb; off = (c - NA8) * 8; }
    f32x4 v0 = *(const f32x4*)(src + off);
    f32x4 v1 = *(const f32x4*)(src + off + 4);
    u32x4 o;
    o[0] = pack_bf2(v0[0], v0[1]);
    o[1] = pack_bf2(v0[2], v0[3]);
    o[2] = pack_bf2(v1[0], v1[1]);
    o[3] = pack_bf2(v1[2], v1[3]);
    *(u32x4*)(dst + off) = o;
  }
}

// ---------------- bf16 grouped GEMM, 32x32x16 MFMA ----------------
// LDS per op per buf: [128 rows][64 k] bf16; swizzle: phys 16B-chunk p of
// row r holds logical chunk p ^ (r&7); linear gload dest + pre-permuted
// global source + XOR'd ds_read (rule 21; verified R5/R9).
__global__ __launch_bounds__(256, 2)
void ggemm_w(const unsigned short* __restrict__ A,
             const unsigned short* __restrict__ B,
             const float* __restrict__ sa,
             const float* __restrict__ sb,
             const int* __restrict__ seg,
             float* __restrict__ C) {
  constexpr int M = 16384, N = 5632, E = 8;
  constexpr int NTC = N / 128;          // 44
  const int nwg = (M / 128) * NTC;      // 5632, % 8 == 0

  // T1 XCD swizzle
  int bid = blockIdx.x;
  int sid = (bid & 7) * (nwg >> 3) + (bid >> 3);
  int mt = sid / NTC, nt = sid % NTC;
  int m0 = mt * 128, n0 = nt * 128;

  int tid = threadIdx.x, lane = tid & 63, w = tid >> 6;
  int wr = (w >> 1) * 64, wc = (w & 1) * 64;   // 2x2 wave grid, 64x64/wave
  int l31 = lane & 31, lk = lane >> 5;         // 32x32 operand coords

  __shared__ unsigned short Asm[2][128 * 64];  // 32 KiB
  __shared__ unsigned short Bsm[2][128 * 64];  // 32 KiB

  // stage source coords (pre-permuted): lane -> row lane>>3, phys chunk lane&7,
  // fetch logical chunk (lane&7) ^ (lane>>3).
  int srow = lane >> 3;
  int scol = ((lane & 7) ^ srow) * 8;
  const unsigned short* gA = A + (size_t)(m0 + w * 32 + srow) * KDIM + scol;

  // ds_read offsets for 32x32x16 fragments:
  // sub-k kq (0..3): lane reads row (tile*32 + l31), k = kq*16 + lk*8
  //   -> logical 16B chunk = kq*2 + lk; phys = chunk ^ (row&7)
  int rA0 = wr + l31, rA1 = wr + 32 + l31;
  int rB0 = wc + l31, rB1 = wc + 32 + l31;
  int xA0[4], xA1[4], xB0[4], xB1[4];
#pragma unroll
  for (int kq = 0; kq < 4; ++kq) {
    int c = kq * 2 + lk;
    xA0[kq] = rA0 * 64 + ((c ^ (rA0 & 7)) * 8);
    xA1[kq] = rA1 * 64 + ((c ^ (rA1 & 7)) * 8);
    xB0[kq] = rB0 * 64 + ((c ^ (rB0 & 7)) * 8);
    xB1[kq] = rB1 * 64 + ((c ^ (rB1 & 7)) * 8);
  }

  for (int e = 0; e < E; ++e) {
    int rlo = max(m0, seg[e]);
    int rhi = min(m0 + 128, seg[e + 1]);
    if (rlo >= rhi) continue;
    const unsigned short* gB =
        B + (size_t)e * N * KDIM + (size_t)(n0 + w * 32 + srow) * KDIM + scol;

    frag_cd16 acc[2][2];
#pragma unroll
    for (int i = 0; i < 2; ++i)
#pragma unroll
      for (int j = 0; j < 2; ++j) acc[i][j] = (frag_cd16)(0.f);

    auto stage = [&](int b, int kt) {
#pragma unroll
      for (int i = 0; i < 4; ++i) {
        gload_lds16(gA + (size_t)i * 8 * KDIM + kt * BK,
                    &Asm[b][(w * 32 + i * 8) * 64]);
        gload_lds16(gB + (size_t)i * 8 * KDIM + kt * BK,
                    &Bsm[b][(w * 32 + i * 8) * 64]);
      }
    };
    auto compute = [&](int b) {
      const unsigned short* pa = &Asm[b][0];
      const unsigned short* pb = &Bsm[b][0];
#pragma unroll
      for (int kq = 0; kq < 4; ++kq) {
        frag_ab a0 = *(const frag_ab*)(pa + xA0[kq]);
        frag_ab a1 = *(const frag_ab*)(pa + xA1[kq]);
        frag_ab b0 = *(const frag_ab*)(pb + xB0[kq]);
        frag_ab b1 = *(const frag_ab*)(pb + xB1[kq]);
        acc[0][0] = __builtin_amdgcn_mfma_f32_32x32x16_bf16(a0, b0, acc[0][0], 0, 0, 0);
        acc[0][1] = __builtin_amdgcn_mfma_f32_32x32x16_bf16(a0, b1, acc[0][1], 0, 0, 0);
        acc[1][0] = __builtin_amdgcn_mfma_f32_32x32x16_bf16(a1, b0, acc[1][0], 0, 0, 0);
        acc[1][1] = __builtin_amdgcn_mfma_f32_32x32x16_bf16(a1, b1, acc[1][1], 0, 0, 0);
      }
    };

    stage(0, 0);
    __syncthreads();
    for (int kt = 0; kt < NKSTEP; ++kt) {
      if (kt + 1 < NKSTEP) stage((kt + 1) & 1, kt + 1);  // issue-early
      compute(kt & 1);
      __syncthreads();
    }

    // epilogue: C/D layout col = lane&31, row = (r&3) + 8*(r>>2) + 4*(lane>>5)
    float sbe = sb[e];
#pragma unroll
    for (int i = 0; i < 2; ++i) {
#pragma unroll
      for (int r = 0; r < 16; ++r) {
        int grow = m0 + wr + i * 32 + (r & 3) + 8 * (r >> 2) + 4 * lk;
        if (grow >= rlo && grow < rhi) {
          float s = sa[grow] * sbe;
          float* Crow = C + (size_t)grow * N + n0 + wc;
#pragma unroll
          for (int j = 0; j < 2; ++j)
            Crow[j * 32 + l31] = acc[i][j][r] * s;
        }
      }
    }
  }
}

extern "C" void kernel_launch(void* const* d_in, const int* in_sizes, int n_in,
                              void* d_out, int out_size, void* d_ws, size_t ws_size,
                              hipStream_t stream) {
  const float* a = (const float*)d_in[0];
  const float* b = (const float*)d_in[1];
  const float* sa = (const float*)d_in[2];
  const float* sb = (const float*)d_in[3];
  const int* seg = (const int*)d_in[4];
  float* out = (float*)d_out;

  constexpr size_t NA = 16384ULL * 2048;
  unsigned short* wa = (unsigned short*)d_ws;
  unsigned short* wb = wa + NA;

  hipLaunchKernelGGL(convert_kernel, dim3(2048), dim3(256), 0, stream, a, b, wa, wb);
  hipLaunchKernelGGL(ggemm_w, dim3(5632), dim3(256), 0, stream,
                     wa, wb, sa, sb, seg, out);
}